// Round 8
// baseline (440.337 us; speedup 1.0000x reference)
//
#include <hip/hip_runtime.h>
#include <hip/hip_bf16.h>

#define N_NODES   50000
#define N_EDGES   800000
#define D         256
#define N_LAYERS  3
#define N_GRAPHS  64
#define LN_EPS    1e-5f
#define NB_SCAN   ((N_NODES + 255) / 256)   // 196

typedef __attribute__((ext_vector_type(8))) short bf16x8;
typedef __attribute__((ext_vector_type(4))) float f32x4;

__device__ __forceinline__ unsigned short f2bf(float f) {
    unsigned int u = __float_as_uint(f);
    unsigned int r = (u + 0x7FFFu + ((u >> 16) & 1u)) >> 16;
    return (unsigned short)r;
}
__device__ __forceinline__ float bf2f(unsigned short h) {
    return __uint_as_float(((unsigned int)h) << 16);
}

// ---------------------------------------------------------------------------
// x (fp32) -> bf16 scaled by dinv[row]  (hs0 = dinv * x)
__global__ void k_xtobf_s(const float* __restrict__ x, const float* __restrict__ dinv,
                          unsigned short* __restrict__ xb) {
    int gid = blockIdx.x * blockDim.x + threadIdx.x;      // one per 8 elems
    int base = gid * 8;
    if (base >= N_NODES * D) return;
    float sc = dinv[base >> 8];
    const float4* x4 = (const float4*)(x + base);
    float4 a = x4[0], b = x4[1];
    ushort4 lo, hi;
    lo.x = f2bf(a.x * sc); lo.y = f2bf(a.y * sc); lo.z = f2bf(a.z * sc); lo.w = f2bf(a.w * sc);
    hi.x = f2bf(b.x * sc); hi.y = f2bf(b.y * sc); hi.z = f2bf(b.z * sc); hi.w = f2bf(b.w * sc);
    ((ushort4*)(xb + base))[0] = lo;
    ((ushort4*)(xb + base))[1] = hi;
}

// W [l][k][n] fp32 -> Wbt [l][n][k] bf16 (transposed for MFMA loads)
__global__ void k_wtrans(const float* __restrict__ W, unsigned short* __restrict__ Wbt) {
    int gid = blockIdx.x * blockDim.x + threadIdx.x;
    if (gid >= N_LAYERS * D * D) return;
    int l = gid >> 16;
    int rem = gid & 65535;
    int n = rem >> 8;
    int k = rem & 255;
    Wbt[(size_t)l * D * D + n * D + k] = f2bf(W[(size_t)l * D * D + k * D + n]);
}

// ---------------------------------------------------------------------------
__global__ void k_indeg(const int* __restrict__ dst, int* __restrict__ indeg) {
    int e = blockIdx.x * blockDim.x + threadIdx.x;
    if (e < N_EDGES) atomicAdd(&indeg[dst[e]], 1);
}

__global__ void k_dinv(const int* __restrict__ indeg, float* __restrict__ dinv) {
    int n = blockIdx.x * blockDim.x + threadIdx.x;
    if (n < N_NODES) dinv[n] = rsqrtf((float)(indeg[n] + 1));
}

__global__ __launch_bounds__(256) void k_bsum(const int* __restrict__ indeg, int* __restrict__ bsum) {
    int b = blockIdx.x, t = threadIdx.x;
    int i = b * 256 + t;
    int v = (i < N_NODES) ? indeg[i] : 0;
#pragma unroll
    for (int m = 32; m >= 1; m >>= 1) v += __shfl_xor(v, m);
    __shared__ int s[4];
    if ((t & 63) == 0) s[t >> 6] = v;
    __syncthreads();
    if (t == 0) bsum[b] = s[0] + s[1] + s[2] + s[3];
}

__global__ __launch_bounds__(256) void k_bscan(const int* __restrict__ bsum, int* __restrict__ bbase) {
    __shared__ int s[256];
    int t = threadIdx.x;
    int v = (t < NB_SCAN) ? bsum[t] : 0;
    s[t] = v;
    __syncthreads();
    for (int off = 1; off < 256; off <<= 1) {
        int tv = (t >= off) ? s[t - off] : 0;
        __syncthreads();
        s[t] += tv;
        __syncthreads();
    }
    if (t < NB_SCAN) bbase[t] = s[t] - v;
}

__global__ __launch_bounds__(256) void k_offsets(const int* __restrict__ indeg, const int* __restrict__ bbase,
                                                 int* __restrict__ offsets, int* __restrict__ cursor) {
    __shared__ int s[256];
    int b = blockIdx.x, t = threadIdx.x;
    int i = b * 256 + t;
    int v = (i < N_NODES) ? indeg[i] : 0;
    s[t] = v;
    __syncthreads();
    for (int off = 1; off < 256; off <<= 1) {
        int tv = (t >= off) ? s[t - off] : 0;
        __syncthreads();
        s[t] += tv;
        __syncthreads();
    }
    if (i < N_NODES) {
        int o = bbase[b] + s[t] - v;
        offsets[i] = o;
        cursor[i]  = o;
    }
}

// CSR fill: store only src index as uint16 (N_NODES < 65536)
__global__ void k_csr_fill(const int* __restrict__ src, const int* __restrict__ dst,
                           int* __restrict__ cursor, unsigned short* __restrict__ esrc) {
    int e = blockIdx.x * blockDim.x + threadIdx.x;
    if (e >= N_EDGES) return;
    int s = src[e], d = dst[e];
    int pos = atomicAdd(&cursor[d], 1);
    esrc[pos] = (unsigned short)s;
}

__global__ void k_counts_bs(const int* __restrict__ batch, int* __restrict__ counts) {
    int g = threadIdx.x;
    if (g >= N_GRAPHS) return;
    int lo = 0, hi = N_NODES;
    while (lo < hi) { int mid = (lo + hi) >> 1; if (batch[mid] < g) lo = mid + 1; else hi = mid; }
    int start = lo;
    lo = 0; hi = N_NODES;
    int g1 = g + 1;
    while (lo < hi) { int mid = (lo + hi) >> 1; if (batch[mid] < g1) lo = mid + 1; else hi = mid; }
    counts[g] = lo - start;
}

// ---------------------------------------------------------------------------
// FUSED layer: gather-aggregate -> LDS A-tile -> MFMA GEMM -> bias+LN+ReLU
// block = 512 thr (8 waves) x 64 output rows.
// Phase 1: wave w aggregates nodes brow+8w..+7 (half-wave per edge, 512 B rows),
//          writes dinv*sum as bf16 into swizzled LDS A-tile.
// Phase 2: W-frags persistent in regs; wave owns 32-col slice; split-LN.
__global__ __launch_bounds__(512) void k_layer(const unsigned short* __restrict__ hs,
                                               const int* __restrict__ offsets,
                                               const int* __restrict__ indeg,
                                               const float* __restrict__ dinv,
                                               const unsigned short* __restrict__ esrc,
                                               const unsigned short* __restrict__ Wbt,
                                               const float* __restrict__ bias,
                                               const float* __restrict__ gamma,
                                               const float* __restrict__ beta,
                                               const float* __restrict__ rowscale,
                                               unsigned short* __restrict__ out) {
    __shared__ short alds[64 * 256];      // 32 KB swizzled A-tile (bf16)
    __shared__ float red[2][8][64];       // 4 KB LN partials
    const int t = threadIdx.x;
    const int lane = t & 63;
    const int w = t >> 6;                 // wave 0..7
    const int lrow = lane & 15;
    const int q = lane >> 4;              // 0..3
    const int brow = blockIdx.x * 64;

    // ---------------- Phase 1: gather-aggregate 8 nodes per wave ----------------
    const int hw = lane >> 5;             // edge-pair slot
    const int dl = lane & 31;             // dim chunk 0..31 (8 dims, 16 B)
    const unsigned short* hp = hs + dl * 8;

    for (int nn = 0; nn < 8; ++nn) {
        int node = brow + w * 8 + nn;
        int nodec = (node < N_NODES) ? node : (N_NODES - 1);

        float acc[8];
        if (hw == 0) {
            bf16x8 v = *(const bf16x8*)(hp + (size_t)nodec * 256);
#pragma unroll
            for (int j = 0; j < 8; ++j) acc[j] = bf2f((unsigned short)v[j]);
        } else {
#pragma unroll
            for (int j = 0; j < 8; ++j) acc[j] = 0.f;
        }

        const int beg = offsets[nodec];
        const int end = beg + indeg[nodec];
        int i = beg + hw;
        for (; i + 6 < end; i += 8) {
            int s0 = esrc[i];
            int s1 = esrc[i + 2];
            int s2 = esrc[i + 4];
            int s3 = esrc[i + 6];
            bf16x8 v0 = *(const bf16x8*)(hp + (size_t)s0 * 256);
            bf16x8 v1 = *(const bf16x8*)(hp + (size_t)s1 * 256);
            bf16x8 v2 = *(const bf16x8*)(hp + (size_t)s2 * 256);
            bf16x8 v3 = *(const bf16x8*)(hp + (size_t)s3 * 256);
#pragma unroll
            for (int j = 0; j < 8; ++j) acc[j] += bf2f((unsigned short)v0[j]);
#pragma unroll
            for (int j = 0; j < 8; ++j) acc[j] += bf2f((unsigned short)v1[j]);
#pragma unroll
            for (int j = 0; j < 8; ++j) acc[j] += bf2f((unsigned short)v2[j]);
#pragma unroll
            for (int j = 0; j < 8; ++j) acc[j] += bf2f((unsigned short)v3[j]);
        }
        for (; i < end; i += 2) {
            int s0 = esrc[i];
            bf16x8 v0 = *(const bf16x8*)(hp + (size_t)s0 * 256);
#pragma unroll
            for (int j = 0; j < 8; ++j) acc[j] += bf2f((unsigned short)v0[j]);
        }

#pragma unroll
        for (int j = 0; j < 8; ++j) acc[j] += __shfl_xor(acc[j], 32);

        if (hw == 0) {
            int r = w * 8 + nn;
            float sc = dinv[nodec];
            bf16x8 o;
#pragma unroll
            for (int j = 0; j < 8; ++j) o[j] = (short)f2bf(acc[j] * sc);
            *(bf16x8*)(alds + r * 256 + (dl ^ (r & 7)) * 8) = o;
        }
    }
    __syncthreads();

    // ---------------- Phase 2: GEMM + bias + LN + ReLU ----------------
    const int ncb = w * 32;               // wave's column base

    bf16x8 wf[2][8];
#pragma unroll
    for (int nt = 0; nt < 2; ++nt) {
        const unsigned short* wp = Wbt + (size_t)(ncb + nt * 16 + lrow) * 256 + q * 8;
#pragma unroll
        for (int ks = 0; ks < 8; ++ks)
            wf[nt][ks] = *(const bf16x8*)(wp + ks * 32);
    }

    f32x4 acc[4][2];
#pragma unroll
    for (int mt = 0; mt < 4; ++mt)
#pragma unroll
        for (int nt = 0; nt < 2; ++nt) acc[mt][nt] = (f32x4){0.f, 0.f, 0.f, 0.f};

#pragma unroll
    for (int ks = 0; ks < 8; ++ks) {
        bf16x8 av[4];
#pragma unroll
        for (int mt = 0; mt < 4; ++mt) {
            int cs = (ks * 4 + q) ^ (lrow & 7);
            av[mt] = *(const bf16x8*)(alds + (mt * 16 + lrow) * 256 + cs * 8);
        }
#pragma unroll
        for (int mt = 0; mt < 4; ++mt) {
            acc[mt][0] = __builtin_amdgcn_mfma_f32_16x16x32_bf16(wf[0][ks], av[mt], acc[mt][0], 0, 0, 0);
            acc[mt][1] = __builtin_amdgcn_mfma_f32_16x16x32_bf16(wf[1][ks], av[mt], acc[mt][1], 0, 0, 0);
        }
    }

    const float4* bias4 = (const float4*)bias;
#pragma unroll
    for (int mt = 0; mt < 4; ++mt) {
        float s = 0.f, s2 = 0.f;
#pragma unroll
        for (int nt = 0; nt < 2; ++nt) {
            float4 bv = bias4[w * 8 + nt * 4 + q];
#pragma unroll
            for (int r = 0; r < 4; ++r) {
                float v = acc[mt][nt][r] + ((const float*)&bv)[r];
                acc[mt][nt][r] = v;
                s += v;
                s2 += v * v;
            }
        }
        s  += __shfl_xor(s, 16);  s  += __shfl_xor(s, 32);
        s2 += __shfl_xor(s2, 16); s2 += __shfl_xor(s2, 32);
        if (lane < 16) {
            red[0][w][mt * 16 + lane] = s;
            red[1][w][mt * 16 + lane] = s2;
        }
    }
    __syncthreads();

    const float4* g4 = (const float4*)gamma;
    const float4* be4 = (const float4*)beta;
#pragma unroll
    for (int mt = 0; mt < 4; ++mt) {
        int r = mt * 16 + lrow;
        float s = 0.f, s2 = 0.f;
#pragma unroll
        for (int j = 0; j < 8; ++j) { s += red[0][j][r]; s2 += red[1][j][r]; }
        float mu = s * (1.0f / 256.0f);
        float var = s2 * (1.0f / 256.0f) - mu * mu;
        float rs = rsqrtf(var + LN_EPS);

        int row = brow + r;
        if (row < N_NODES) {
            float sc = (rowscale != nullptr) ? rowscale[row] : 1.0f;
#pragma unroll
            for (int nt = 0; nt < 2; ++nt) {
                float4 gv = g4[w * 8 + nt * 4 + q];
                float4 bev = be4[w * 8 + nt * 4 + q];
                ushort4 o;
                float v0 = fmaxf((acc[mt][nt][0] - mu) * rs * gv.x + bev.x, 0.f) * sc;
                float v1 = fmaxf((acc[mt][nt][1] - mu) * rs * gv.y + bev.y, 0.f) * sc;
                float v2 = fmaxf((acc[mt][nt][2] - mu) * rs * gv.z + bev.z, 0.f) * sc;
                float v3 = fmaxf((acc[mt][nt][3] - mu) * rs * gv.w + bev.w, 0.f) * sc;
                o.x = f2bf(v0); o.y = f2bf(v1); o.z = f2bf(v2); o.w = f2bf(v3);
                *(ushort4*)(out + (size_t)row * 256 + ncb + nt * 16 + q * 4) = o;
            }
        }
    }
}

// ---------------------------------------------------------------------------
__global__ __launch_bounds__(256) void k_pool(const unsigned short* __restrict__ h,
                                              const int* __restrict__ batch,
                                              float* __restrict__ sums) {
    __shared__ int sb[128];
    int t = threadIdx.x;
    int n0 = blockIdx.x * 128;
    int cnt = N_NODES - n0; if (cnt > 128) cnt = 128;
    if (cnt <= 0) return;
    if (t < cnt) sb[t] = batch[n0 + t];
    __syncthreads();

    float acc = 0.f;
    int g = sb[0];
    for (int i = 0; i < cnt; ++i) {
        int bg = sb[i];
        if (bg != g) {
            atomicAdd(&sums[g * 256 + t], acc);
            acc = 0.f;
            g = bg;
        }
        acc += bf2f(h[(size_t)(n0 + i) * 256 + t]);
    }
    atomicAdd(&sums[g * 256 + t], acc);
}

__global__ void k_finalize(const float* __restrict__ sums, const int* __restrict__ counts,
                           float* __restrict__ out) {
    int idx = blockIdx.x * blockDim.x + threadIdx.x;
    if (idx < N_GRAPHS * 256) {
        float c = (float)counts[idx >> 8];
        out[idx] = sums[idx] / fmaxf(c, 1.f);
    }
}

// ---------------------------------------------------------------------------
extern "C" void kernel_launch(void* const* d_in, const int* in_sizes, int n_in,
                              void* d_out, int out_size, void* d_ws, size_t ws_size,
                              hipStream_t stream) {
    const float* x     = (const float*)d_in[0];
    const int*   ei    = (const int*)d_in[1];
    const int*   batch = (const int*)d_in[2];
    const float* Ws    = (const float*)d_in[3];
    const float* bs    = (const float*)d_in[4];
    const float* gammas= (const float*)d_in[5];
    const float* betas = (const float*)d_in[6];
    float* out = (float*)d_out;

    const int* src = ei;
    const int* dst = ei + N_EDGES;

    char* p = (char*)d_ws;
    unsigned short* hbfA  = (unsigned short*)p; p += (size_t)N_NODES * D * 2;   // 25.6 MB
    unsigned short* hbfB  = (unsigned short*)p; p += (size_t)N_NODES * D * 2;   // 25.6 MB
    unsigned short* Wbt   = (unsigned short*)p; p += (size_t)N_LAYERS * D * D * 2;
    int*   indeg  = (int*)p;   p += (size_t)N_NODES * 4;
    int*   offs   = (int*)p;   p += (size_t)N_NODES * 4;
    int*   cursor = (int*)p;   p += (size_t)N_NODES * 4;
    float* dinv   = (float*)p; p += (size_t)N_NODES * 4;
    int*   bsum   = (int*)p;   p += (size_t)NB_SCAN * 4;
    int*   bbase  = (int*)p;   p += (size_t)NB_SCAN * 4;
    unsigned short* esrc = (unsigned short*)p; p += (size_t)N_EDGES * 2;
    float* sums   = (float*)p; p += (size_t)N_GRAPHS * D * 4;
    int*   counts = (int*)p;   p += (size_t)N_GRAPHS * 4;

    hipMemsetAsync(indeg, 0, (size_t)N_NODES * 4, stream);
    hipMemsetAsync(sums, 0, (size_t)N_GRAPHS * D * 4, stream);

    // graph preprocessing
    k_indeg <<<(N_EDGES + 255) / 256, 256, 0, stream>>>(dst, indeg);
    k_dinv  <<<NB_SCAN, 256, 0, stream>>>(indeg, dinv);
    k_xtobf_s<<<(N_NODES * D / 8 + 255) / 256, 256, 0, stream>>>(x, dinv, hbfA);
    k_wtrans<<<(N_LAYERS * D * D + 255) / 256, 256, 0, stream>>>(Ws, Wbt);
    k_bsum  <<<NB_SCAN, 256, 0, stream>>>(indeg, bsum);
    k_bscan <<<1, 256, 0, stream>>>(bsum, bbase);
    k_offsets<<<NB_SCAN, 256, 0, stream>>>(indeg, bbase, offs, cursor);
    k_csr_fill<<<(N_EDGES + 255) / 256, 256, 0, stream>>>(src, dst, cursor, esrc);
    k_counts_bs<<<1, 64, 0, stream>>>(batch, counts);

    // 3 fused GCN layers (aggregate-first; hs = dinv*h carried between layers)
    const int layer_grid = (N_NODES + 63) / 64;
    unsigned short* bufs[2] = {hbfA, hbfB};
    for (int l = 0; l < N_LAYERS; ++l) {
        const unsigned short* in_h = bufs[l & 1];
        unsigned short* out_h      = bufs[(l + 1) & 1];
        const float* rsc = (l == N_LAYERS - 1) ? nullptr : dinv;
        k_layer<<<layer_grid, 512, 0, stream>>>(in_h, offs, indeg, dinv, esrc,
                                                Wbt + (size_t)l * D * D,
                                                bs + (size_t)l * D,
                                                gammas + (size_t)l * D,
                                                betas + (size_t)l * D, rsc, out_h);
    }

    // global mean pool (last layer wrote unscaled h)
    unsigned short* hfin = bufs[N_LAYERS & 1];
    k_pool<<<(N_NODES + 127) / 128, 256, 0, stream>>>(hfin, batch, sums);
    k_finalize<<<(N_GRAPHS * 256 + 255) / 256, 256, 0, stream>>>(sums, counts, out);
}

// Round 9
// 417.751 us; speedup vs baseline: 1.0541x; 1.0541x over previous
//
#include <hip/hip_runtime.h>
#include <hip/hip_bf16.h>

#define N_NODES   50000
#define N_EDGES   800000
#define D         256
#define N_LAYERS  3
#define N_GRAPHS  64
#define LN_EPS    1e-5f
#define NB_SCAN   ((N_NODES + 255) / 256)   // 196

typedef __attribute__((ext_vector_type(8))) short bf16x8;
typedef __attribute__((ext_vector_type(4))) float f32x4;

__device__ __forceinline__ unsigned short f2bf(float f) {
    unsigned int u = __float_as_uint(f);
    unsigned int r = (u + 0x7FFFu + ((u >> 16) & 1u)) >> 16;
    return (unsigned short)r;
}
__device__ __forceinline__ float bf2f(unsigned short h) {
    return __uint_as_float(((unsigned int)h) << 16);
}

// ---------------------------------------------------------------------------
// x (fp32) -> bf16 scaled by dinv[row]  (hs0 = dinv * x)
__global__ void k_xtobf_s(const float* __restrict__ x, const float* __restrict__ dinv,
                          unsigned short* __restrict__ xb) {
    int gid = blockIdx.x * blockDim.x + threadIdx.x;      // one per 8 elems
    int base = gid * 8;
    if (base >= N_NODES * D) return;
    float sc = dinv[base >> 8];
    const float4* x4 = (const float4*)(x + base);
    float4 a = x4[0], b = x4[1];
    ushort4 lo, hi;
    lo.x = f2bf(a.x * sc); lo.y = f2bf(a.y * sc); lo.z = f2bf(a.z * sc); lo.w = f2bf(a.w * sc);
    hi.x = f2bf(b.x * sc); hi.y = f2bf(b.y * sc); hi.z = f2bf(b.z * sc); hi.w = f2bf(b.w * sc);
    ((ushort4*)(xb + base))[0] = lo;
    ((ushort4*)(xb + base))[1] = hi;
}

// W [l][k][n] fp32 -> Wbt [l][n][k] bf16 (transposed for MFMA loads)
__global__ void k_wtrans(const float* __restrict__ W, unsigned short* __restrict__ Wbt) {
    int gid = blockIdx.x * blockDim.x + threadIdx.x;
    if (gid >= N_LAYERS * D * D) return;
    int l = gid >> 16;
    int rem = gid & 65535;
    int n = rem >> 8;
    int k = rem & 255;
    Wbt[(size_t)l * D * D + n * D + k] = f2bf(W[(size_t)l * D * D + k * D + n]);
}

// ---------------------------------------------------------------------------
__global__ void k_indeg(const int* __restrict__ dst, int* __restrict__ indeg) {
    int e = blockIdx.x * blockDim.x + threadIdx.x;
    if (e < N_EDGES) atomicAdd(&indeg[dst[e]], 1);
}

// fused: dinv + per-block degree sums
__global__ __launch_bounds__(256) void k_dinv_bsum(const int* __restrict__ indeg,
                                                   float* __restrict__ dinv,
                                                   int* __restrict__ bsum) {
    int b = blockIdx.x, t = threadIdx.x;
    int i = b * 256 + t;
    int v = (i < N_NODES) ? indeg[i] : 0;
    if (i < N_NODES) dinv[i] = rsqrtf((float)(v + 1));
    int s = v;
#pragma unroll
    for (int m = 32; m >= 1; m >>= 1) s += __shfl_xor(s, m);
    __shared__ int sh[4];
    if ((t & 63) == 0) sh[t >> 6] = s;
    __syncthreads();
    if (t == 0) bsum[b] = sh[0] + sh[1] + sh[2] + sh[3];
}

// fused: scan of block sums + per-graph counts (binary search on sorted batch)
__global__ __launch_bounds__(256) void k_bscan_counts(const int* __restrict__ bsum,
                                                      int* __restrict__ bbase,
                                                      const int* __restrict__ batch,
                                                      int* __restrict__ counts) {
    int t = threadIdx.x;
    if (t < N_GRAPHS) {
        int g = t;
        int lo = 0, hi = N_NODES;
        while (lo < hi) { int mid = (lo + hi) >> 1; if (batch[mid] < g) lo = mid + 1; else hi = mid; }
        int start = lo;
        lo = 0; hi = N_NODES;
        int g1 = g + 1;
        while (lo < hi) { int mid = (lo + hi) >> 1; if (batch[mid] < g1) lo = mid + 1; else hi = mid; }
        counts[g] = lo - start;
    }
    __shared__ int s[256];
    int v = (t < NB_SCAN) ? bsum[t] : 0;
    s[t] = v;
    __syncthreads();
    for (int off = 1; off < 256; off <<= 1) {
        int tv = (t >= off) ? s[t - off] : 0;
        __syncthreads();
        s[t] += tv;
        __syncthreads();
    }
    if (t < NB_SCAN) bbase[t] = s[t] - v;
}

__global__ __launch_bounds__(256) void k_offsets(const int* __restrict__ indeg, const int* __restrict__ bbase,
                                                 int* __restrict__ offsets, int* __restrict__ cursor) {
    __shared__ int s[256];
    int b = blockIdx.x, t = threadIdx.x;
    int i = b * 256 + t;
    int v = (i < N_NODES) ? indeg[i] : 0;
    s[t] = v;
    __syncthreads();
    for (int off = 1; off < 256; off <<= 1) {
        int tv = (t >= off) ? s[t - off] : 0;
        __syncthreads();
        s[t] += tv;
        __syncthreads();
    }
    if (i < N_NODES) {
        int o = bbase[b] + s[t] - v;
        offsets[i] = o;
        cursor[i]  = o;
    }
}

// CSR fill: store only src index as uint16 (N_NODES < 65536)
__global__ void k_csr_fill(const int* __restrict__ src, const int* __restrict__ dst,
                           int* __restrict__ cursor, unsigned short* __restrict__ esrc) {
    int e = blockIdx.x * blockDim.x + threadIdx.x;
    if (e >= N_EDGES) return;
    int s = src[e], d = dst[e];
    int pos = atomicAdd(&cursor[d], 1);
    esrc[pos] = (unsigned short)s;
}

// ---------------------------------------------------------------------------
// aggregate: agg[n] = dinv[n] * (hs[n] + sum_edges hs[src])
// one wave per node; half-wave (32 lanes x 16 B) covers a full 512 B row;
// 4 edges per half-wave iteration -> 8 rows in flight per wave.
__global__ __launch_bounds__(256) void k_agg(const unsigned short* __restrict__ h,
                                             const int* __restrict__ offsets,
                                             const int* __restrict__ indeg,
                                             const float* __restrict__ dinv,
                                             const unsigned short* __restrict__ esrc,
                                             unsigned short* __restrict__ outA) {
    const int node = blockIdx.x * 4 + (threadIdx.x >> 6);
    const int lane = threadIdx.x & 63;
    if (node >= N_NODES) return;
    const int hw = lane >> 5;       // which edge of the interleaved pair
    const int dl = lane & 31;       // dim-lane: dims dl*8 .. dl*8+7
    const unsigned short* hp = h + dl * 8;

    float acc[8];
    if (hw == 0) {
        bf16x8 v = *(const bf16x8*)(hp + (size_t)node * 256);
#pragma unroll
        for (int j = 0; j < 8; ++j) acc[j] = bf2f((unsigned short)v[j]);
    } else {
#pragma unroll
        for (int j = 0; j < 8; ++j) acc[j] = 0.f;
    }

    const int beg = offsets[node];
    const int end = beg + indeg[node];
    int i = beg + hw;
    for (; i + 6 < end; i += 8) {
        int s0 = esrc[i];
        int s1 = esrc[i + 2];
        int s2 = esrc[i + 4];
        int s3 = esrc[i + 6];
        bf16x8 v0 = *(const bf16x8*)(hp + (size_t)s0 * 256);
        bf16x8 v1 = *(const bf16x8*)(hp + (size_t)s1 * 256);
        bf16x8 v2 = *(const bf16x8*)(hp + (size_t)s2 * 256);
        bf16x8 v3 = *(const bf16x8*)(hp + (size_t)s3 * 256);
#pragma unroll
        for (int j = 0; j < 8; ++j) acc[j] += bf2f((unsigned short)v0[j]);
#pragma unroll
        for (int j = 0; j < 8; ++j) acc[j] += bf2f((unsigned short)v1[j]);
#pragma unroll
        for (int j = 0; j < 8; ++j) acc[j] += bf2f((unsigned short)v2[j]);
#pragma unroll
        for (int j = 0; j < 8; ++j) acc[j] += bf2f((unsigned short)v3[j]);
    }
    for (; i < end; i += 2) {
        int s0 = esrc[i];
        bf16x8 v0 = *(const bf16x8*)(hp + (size_t)s0 * 256);
#pragma unroll
        for (int j = 0; j < 8; ++j) acc[j] += bf2f((unsigned short)v0[j]);
    }

#pragma unroll
    for (int j = 0; j < 8; ++j) acc[j] += __shfl_xor(acc[j], 32);

    if (hw == 0) {
        float sc = dinv[node];
        bf16x8 o;
#pragma unroll
        for (int j = 0; j < 8; ++j) o[j] = (short)f2bf(acc[j] * sc);
        *(bf16x8*)(outA + (size_t)node * 256 + dl * 8) = o;
    }
}

// ---------------------------------------------------------------------------
// fused GEMM + bias + LayerNorm + ReLU, two-tile pipelined (issue-early staging)
// block = 512 thr (8 waves); handles tiles 2b, 2b+1 (64 rows each).
// Tile t+1's global loads issue BEFORE tile t's MFMA consumes LDS; ds_write
// lands after the post-compute barrier. W-frags persistent in regs.
__global__ __launch_bounds__(512) void k_gemm_ln(const unsigned short* __restrict__ A,
                                                 const unsigned short* __restrict__ Wbt,
                                                 const float* __restrict__ bias,
                                                 const float* __restrict__ gamma,
                                                 const float* __restrict__ beta,
                                                 const float* __restrict__ rowscale,
                                                 unsigned short* __restrict__ out) {
    __shared__ short alds[64 * 256];      // 32 KB swizzled A-tile
    __shared__ float red[2][8][64];       // 4 KB LN partials
    const int t = threadIdx.x;
    const int lane = t & 63;
    const int w = t >> 6;                 // wave 0..7
    const int lrow = lane & 15;
    const int q = lane >> 4;              // 0..3
    const int ncb = w * 32;               // wave's column base
    const int tile0 = blockIdx.x * 2;

    // persistent W fragments (L2-resident)
    bf16x8 wf[2][8];
#pragma unroll
    for (int nt = 0; nt < 2; ++nt) {
        const unsigned short* wp = Wbt + (size_t)(ncb + nt * 16 + lrow) * 256 + q * 8;
#pragma unroll
        for (int ks = 0; ks < 8; ++ks)
            wf[nt][ks] = *(const bf16x8*)(wp + ks * 32);
    }

    // per-thread staging slots: L = it*512 + t -> row r=L>>5, chunk c=L&31
    int srow[4], schk[4];
#pragma unroll
    for (int it = 0; it < 4; ++it) {
        int L = it * 512 + t;
        srow[it] = L >> 5;
        schk[it] = L & 31;
    }

    // stage tile0
    bf16x8 sreg[4];
#pragma unroll
    for (int it = 0; it < 4; ++it) {
        int row = tile0 * 64 + srow[it]; if (row >= N_NODES) row = N_NODES - 1;
        sreg[it] = *(const bf16x8*)(A + (size_t)row * 256 + schk[it] * 8);
    }
#pragma unroll
    for (int it = 0; it < 4; ++it)
        *(bf16x8*)(alds + srow[it] * 256 + (schk[it] ^ (srow[it] & 7)) * 8) = sreg[it];
    __syncthreads();

    const float4* bias4 = (const float4*)bias;
    const float4* g4 = (const float4*)gamma;
    const float4* be4 = (const float4*)beta;

#pragma unroll
    for (int tt = 0; tt < 2; ++tt) {
        const int brow = (tile0 + tt) * 64;

        // issue next tile's global loads early (latency hides under MFMA+LN)
        if (tt == 0) {
#pragma unroll
            for (int it = 0; it < 4; ++it) {
                int row = (tile0 + 1) * 64 + srow[it]; if (row >= N_NODES) row = N_NODES - 1;
                sreg[it] = *(const bf16x8*)(A + (size_t)row * 256 + schk[it] * 8);
            }
        }

        // compute
        f32x4 acc[4][2];
#pragma unroll
        for (int mt = 0; mt < 4; ++mt)
#pragma unroll
            for (int nt = 0; nt < 2; ++nt) acc[mt][nt] = (f32x4){0.f, 0.f, 0.f, 0.f};

#pragma unroll
        for (int ks = 0; ks < 8; ++ks) {
            bf16x8 av[4];
#pragma unroll
            for (int mt = 0; mt < 4; ++mt) {
                int cs = (ks * 4 + q) ^ (lrow & 7);
                av[mt] = *(const bf16x8*)(alds + (mt * 16 + lrow) * 256 + cs * 8);
            }
#pragma unroll
            for (int mt = 0; mt < 4; ++mt) {
                acc[mt][0] = __builtin_amdgcn_mfma_f32_16x16x32_bf16(wf[0][ks], av[mt], acc[mt][0], 0, 0, 0);
                acc[mt][1] = __builtin_amdgcn_mfma_f32_16x16x32_bf16(wf[1][ks], av[mt], acc[mt][1], 0, 0, 0);
            }
        }

        // bias + per-wave LN partials
#pragma unroll
        for (int mt = 0; mt < 4; ++mt) {
            float s = 0.f, s2 = 0.f;
#pragma unroll
            for (int nt = 0; nt < 2; ++nt) {
                float4 bv = bias4[w * 8 + nt * 4 + q];
#pragma unroll
                for (int r = 0; r < 4; ++r) {
                    float v = acc[mt][nt][r] + ((const float*)&bv)[r];
                    acc[mt][nt][r] = v;
                    s += v;
                    s2 += v * v;
                }
            }
            s  += __shfl_xor(s, 16);  s  += __shfl_xor(s, 32);
            s2 += __shfl_xor(s2, 16); s2 += __shfl_xor(s2, 32);
            if (lane < 16) {
                red[0][w][mt * 16 + lane] = s;
                red[1][w][mt * 16 + lane] = s2;
            }
        }
        __syncthreads();   // red ready; all alds reads of this tile complete

        // overwrite alds with next tile (staged regs) — disjoint from red
        if (tt == 0) {
#pragma unroll
            for (int it = 0; it < 4; ++it)
                *(bf16x8*)(alds + srow[it] * 256 + (schk[it] ^ (srow[it] & 7)) * 8) = sreg[it];
        }

        // LN finish + store
#pragma unroll
        for (int mt = 0; mt < 4; ++mt) {
            int r = mt * 16 + lrow;
            float s = 0.f, s2 = 0.f;
#pragma unroll
            for (int j = 0; j < 8; ++j) { s += red[0][j][r]; s2 += red[1][j][r]; }
            float mu = s * (1.0f / 256.0f);
            float var = s2 * (1.0f / 256.0f) - mu * mu;
            float rs = rsqrtf(var + LN_EPS);

            int row = brow + r;
            if (row < N_NODES) {
                float sc = (rowscale != nullptr) ? rowscale[row] : 1.0f;
#pragma unroll
                for (int nt = 0; nt < 2; ++nt) {
                    float4 gv = g4[w * 8 + nt * 4 + q];
                    float4 bev = be4[w * 8 + nt * 4 + q];
                    ushort4 o;
                    float v0 = fmaxf((acc[mt][nt][0] - mu) * rs * gv.x + bev.x, 0.f) * sc;
                    float v1 = fmaxf((acc[mt][nt][1] - mu) * rs * gv.y + bev.y, 0.f) * sc;
                    float v2 = fmaxf((acc[mt][nt][2] - mu) * rs * gv.z + bev.z, 0.f) * sc;
                    float v3 = fmaxf((acc[mt][nt][3] - mu) * rs * gv.w + bev.w, 0.f) * sc;
                    o.x = f2bf(v0); o.y = f2bf(v1); o.z = f2bf(v2); o.w = f2bf(v3);
                    *(ushort4*)(out + (size_t)row * 256 + ncb + nt * 16 + q * 4) = o;
                }
            }
        }
        __syncthreads();   // red reads done; alds(A1) writes visible for next iter
    }
}

// ---------------------------------------------------------------------------
__global__ __launch_bounds__(256) void k_pool(const unsigned short* __restrict__ h,
                                              const int* __restrict__ batch,
                                              float* __restrict__ sums) {
    __shared__ int sb[128];
    int t = threadIdx.x;
    int n0 = blockIdx.x * 128;
    int cnt = N_NODES - n0; if (cnt > 128) cnt = 128;
    if (cnt <= 0) return;
    if (t < cnt) sb[t] = batch[n0 + t];
    __syncthreads();

    float acc = 0.f;
    int g = sb[0];
    for (int i = 0; i < cnt; ++i) {
        int bg = sb[i];
        if (bg != g) {
            atomicAdd(&sums[g * 256 + t], acc);
            acc = 0.f;
            g = bg;
        }
        acc += bf2f(h[(size_t)(n0 + i) * 256 + t]);
    }
    atomicAdd(&sums[g * 256 + t], acc);
}

__global__ void k_finalize(const float* __restrict__ sums, const int* __restrict__ counts,
                           float* __restrict__ out) {
    int idx = blockIdx.x * blockDim.x + threadIdx.x;
    if (idx < N_GRAPHS * 256) {
        float c = (float)counts[idx >> 8];
        out[idx] = sums[idx] / fmaxf(c, 1.f);
    }
}

// ---------------------------------------------------------------------------
extern "C" void kernel_launch(void* const* d_in, const int* in_sizes, int n_in,
                              void* d_out, int out_size, void* d_ws, size_t ws_size,
                              hipStream_t stream) {
    const float* x     = (const float*)d_in[0];
    const int*   ei    = (const int*)d_in[1];
    const int*   batch = (const int*)d_in[2];
    const float* Ws    = (const float*)d_in[3];
    const float* bs    = (const float*)d_in[4];
    const float* gammas= (const float*)d_in[5];
    const float* betas = (const float*)d_in[6];
    float* out = (float*)d_out;

    const int* src = ei;
    const int* dst = ei + N_EDGES;

    char* p = (char*)d_ws;
    unsigned short* hbf   = (unsigned short*)p; p += (size_t)N_NODES * D * 2;   // 25.6 MB
    unsigned short* aggx  = (unsigned short*)p; p += (size_t)N_NODES * D * 2;   // 25.6 MB
    unsigned short* Wbt   = (unsigned short*)p; p += (size_t)N_LAYERS * D * D * 2;
    int*   indeg  = (int*)p;   p += (size_t)N_NODES * 4;
    int*   offs   = (int*)p;   p += (size_t)N_NODES * 4;
    int*   cursor = (int*)p;   p += (size_t)N_NODES * 4;
    float* dinv   = (float*)p; p += (size_t)N_NODES * 4;
    int*   bsum   = (int*)p;   p += (size_t)NB_SCAN * 4;
    int*   bbase  = (int*)p;   p += (size_t)NB_SCAN * 4;
    unsigned short* esrc = (unsigned short*)p; p += (size_t)N_EDGES * 2;
    float* sums   = (float*)p; p += (size_t)N_GRAPHS * D * 4;
    int*   counts = (int*)p;   p += (size_t)N_GRAPHS * 4;

    hipMemsetAsync(indeg, 0, (size_t)N_NODES * 4, stream);
    hipMemsetAsync(sums, 0, (size_t)N_GRAPHS * D * 4, stream);

    // graph preprocessing
    k_indeg <<<(N_EDGES + 255) / 256, 256, 0, stream>>>(dst, indeg);
    k_dinv_bsum<<<NB_SCAN, 256, 0, stream>>>(indeg, dinv, bsum);
    k_xtobf_s<<<(N_NODES * D / 8 + 255) / 256, 256, 0, stream>>>(x, dinv, hbf);
    k_wtrans<<<(N_LAYERS * D * D + 255) / 256, 256, 0, stream>>>(Ws, Wbt);
    k_bscan_counts<<<1, 256, 0, stream>>>(bsum, bbase, batch, counts);
    k_offsets<<<NB_SCAN, 256, 0, stream>>>(indeg, bbase, offs, cursor);
    k_csr_fill<<<(N_EDGES + 255) / 256, 256, 0, stream>>>(src, dst, cursor, esrc);

    // 3 GCN layers: aggregate-first; hs = dinv*h carried between layers
    const int agg_grid  = (N_NODES + 3) / 4;
    const int gemm_grid = (N_NODES + 127) / 128;   // 2 tiles of 64 rows per block
    for (int l = 0; l < N_LAYERS; ++l) {
        k_agg<<<agg_grid, 256, 0, stream>>>(hbf, offs, indeg, dinv, esrc, aggx);
        const float* rsc = (l == N_LAYERS - 1) ? nullptr : dinv;
        k_gemm_ln<<<gemm_grid, 512, 0, stream>>>(aggx, Wbt + (size_t)l * D * D,
                                                 bs + (size_t)l * D,
                                                 gammas + (size_t)l * D,
                                                 betas + (size_t)l * D, rsc, hbf);
    }

    // global mean pool (last layer wrote unscaled h)
    k_pool<<<(N_NODES + 127) / 128, 256, 0, stream>>>(hbf, batch, sums);
    k_finalize<<<(N_GRAPHS * 256 + 255) / 256, 256, 0, stream>>>(sums, counts, out);
}